// Round 9
// baseline (554.424 us; speedup 1.0000x reference)
//
#include <hip/hip_runtime.h>
#include <math.h>

#define HD   64
#define EIN  8
#define SAS  168          // sA/sW1 row stride in u16 (336 B): bank step 20 -> conflict-light
#define W2S  72           // sW2 row stride in u16 (144 B)
#define NORM_INV 0.01f
#define NTH  512          // 8 waves/block, one shared weight copy
#define NBLK 512          // 2 blocks/CU x 256 CUs
#define NWAVES (NBLK * (NTH / 64))

typedef short bf16x8 __attribute__((ext_vector_type(8)));
typedef float f32x4  __attribute__((ext_vector_type(4)));
typedef float f4v    __attribute__((ext_vector_type(4)));

__device__ __forceinline__ unsigned short f2bf(float f) {
    union { float f; unsigned u; } v; v.f = f;
    unsigned r = v.u + 0x7FFFu + ((v.u >> 16) & 1u);
    return (unsigned short)(r >> 16);
}
__device__ __forceinline__ unsigned pk2(float a, float b) {
    return (unsigned)f2bf(a) | ((unsigned)f2bf(b) << 16);
}
__device__ __forceinline__ float silu_f(float x) {
    return x * __builtin_amdgcn_rcpf(1.0f + __expf(-x));
}

__global__ void prep_out_kernel(const float* __restrict__ coord,
                                float* __restrict__ out, int n3) {
    int i = blockIdx.x * blockDim.x + threadIdx.x;
    if (i < n3) out[i] = coord[i];
}

// r5's proven barrier-free wave-owned pipeline at r8's occupancy:
// 512-thread blocks (8 waves share one LDS weight copy, 2 blocks/CU = 16
// waves/CU), fp32 h gathered from the HIP-owned input buffer with inline
// bf16 conversion (r8 showed d_ws gathers amplify L2-miss traffic ~3x).
// No register prefetch (r6/r7: compiler sinks or spills it).
__global__ __launch_bounds__(NTH, 4) void egnn_mfma_kernel(
    const float* __restrict__ h,      // [N][64] fp32
    const float* __restrict__ coord,
    const int*   __restrict__ eidx,   // [2][E]
    const float* __restrict__ eattr,  // [E][8]
    const float* __restrict__ W1f,    // [136][64] fp32
    const float* __restrict__ W2f,    // [64][64] fp32
    const float* __restrict__ b1,
    const float* __restrict__ b2,
    const float* __restrict__ W3,
    float* __restrict__ out,
    int E_)
{
    __shared__ unsigned short sW1[64 * SAS];      // 21504 B
    __shared__ unsigned short sW2[64 * W2S];      //  9216 B
    __shared__ float sB1[64], sB2[64], sW3[64];   //   768 B
    __shared__ unsigned short sA[128 * SAS];      // 43008 B (8 waves x 16 rows)

    const int t = threadIdx.x;

    // ---- weights -> LDS (once per block) ----
    for (int i = t; i < 136 * 64; i += NTH) {
        int k = i >> 6, n = i & 63;
        sW1[n * SAS + k] = f2bf(W1f[i]);
    }
    for (int i = t; i < 24 * 64; i += NTH) {      // zero-pad W1 k=136..159
        int n = i / 24, k = 136 + (i - n * 24);
        sW1[n * SAS + k] = 0;
    }
    for (int i = t; i < 64 * 64; i += NTH) {
        int k = i >> 6, n = i & 63;
        sW2[n * W2S + k] = f2bf(W2f[i]);
    }
    if (t < 64) sB1[t] = b1[t];
    else if (t < 128) sB2[t - 64] = b2[t - 64];
    else if (t < 192) sW3[t - 128] = W3[t - 128];
    __syncthreads();                               // the ONLY barrier

    const int w = t >> 6, lane = t & 63;
    const int m = lane & 15, q = lane >> 4;
    const int sm = lane >> 2, sp = lane & 3;       // staging: 4 lanes per edge

    unsigned short* stageRow = sA + (16 * w + sm) * SAS;
    unsigned short* fragRow  = sA + (16 * w + m) * SAS;

    // zero-pad k=136..159 of this wave's rows once (X1 aliases only k=0..63)
    if (sp < 3) {
        uint4 z; z.x = 0; z.y = 0; z.z = 0; z.w = 0;
        *((uint4*)(stageRow + 136 + sp * 8)) = z;
    }

    const int ngroups = (E_ + 15) >> 4;
    for (int g = blockIdx.x * (NTH / 64) + w; g < ngroups; g += NWAVES) {
        // ---------- stage 16 edges (this wave's rows; inline cvt) ----------
        int node;
        {
            int e = g * 16 + sm;
            int ec = (e < E_) ? e : (E_ - 1);
            node = (sp < 2) ? eidx[ec] : eidx[(size_t)E_ + ec];
            uint4* dst = (uint4*)stageRow + sp * 4;    // k in [32*sp, 32*sp+32)
            const f4v* src = (const f4v*)(h + (size_t)node * HD) + (sp & 1) * 8;
#pragma unroll
            for (int i = 0; i < 4; ++i) {
                f4v a = src[2 * i], b = src[2 * i + 1];
                uint4 v;
                v.x = pk2(a.x, a.y); v.y = pk2(a.z, a.w);
                v.z = pk2(b.x, b.y); v.w = pk2(b.z, b.w);
                dst[i] = v;
            }
            if (sp & 1) {                              // edge_attr k=128..135
                f4v ep = ((const f4v*)(eattr + (size_t)ec * EIN))[sp >> 1];
                uint2 v; v.x = pk2(ep.x, ep.y); v.y = pk2(ep.z, ep.w);
                *((uint2*)(stageRow + 128 + (sp >> 1) * 4)) = v;
            }
        }

        // epilogue indices via shfl (no eidx re-read); coord loads issued early
        int rI = __shfl(node, 4 * m);
        int cI = __shfl(node, 4 * m + 2);
        float cr = 0.f, cc = 0.f;
        if (q < 3) { cr = coord[rI * 3 + q]; cc = coord[cI * 3 + q]; }

        // ---------- layer 1: D1[n2][e] = sum_k W1[n2][k] * inp[e][k] ----------
        f32x4 acc1[4] = {};
#pragma unroll
        for (int s = 0; s < 5; ++s) {
            bf16x8 bfrag = *(const bf16x8*)(fragRow + s * 32 + q * 8);
#pragma unroll
            for (int nt = 0; nt < 4; ++nt) {
                bf16x8 afrag = *(const bf16x8*)(sW1 + (16 * nt + m) * SAS + s * 32 + q * 8);
                acc1[nt] = __builtin_amdgcn_mfma_f32_16x16x32_bf16(afrag, bfrag, acc1[nt], 0, 0, 0);
            }
        }

        // silu(+b1) -> X1 at row offset 0 (k=0..63), packed b64 per lane
#pragma unroll
        for (int nt = 0; nt < 4; ++nt) {
            float4 bb = *(const float4*)(&sB1[16 * nt + 4 * q]);
            ushort4 o;
            o.x = f2bf(silu_f(acc1[nt][0] + bb.x));
            o.y = f2bf(silu_f(acc1[nt][1] + bb.y));
            o.z = f2bf(silu_f(acc1[nt][2] + bb.z));
            o.w = f2bf(silu_f(acc1[nt][3] + bb.w));
            *((ushort4*)(fragRow + 16 * nt + 4 * q)) = o;
        }

        // ---------- layer 2: D2[n2][e] = sum_k W2[n2][k] * X1[e][k] ----------
        f32x4 acc2[4] = {};
#pragma unroll
        for (int s = 0; s < 2; ++s) {
            bf16x8 bfrag = *(const bf16x8*)(fragRow + s * 32 + q * 8);
#pragma unroll
            for (int nt = 0; nt < 4; ++nt) {
                bf16x8 afrag = *(const bf16x8*)(sW2 + (16 * nt + m) * W2S + s * 32 + q * 8);
                acc2[nt] = __builtin_amdgcn_mfma_f32_16x16x32_bf16(afrag, bfrag, acc2[nt], 0, 0, 0);
            }
        }

        // ---------- epilogue: scal = silu(X2) . W3, all in registers ----------
        float p = 0.f;
#pragma unroll
        for (int nt = 0; nt < 4; ++nt) {
            float4 b2v = *(const float4*)(&sB2[16 * nt + 4 * q]);
            float4 w3v = *(const float4*)(&sW3[16 * nt + 4 * q]);
            p = fmaf(silu_f(acc2[nt][0] + b2v.x), w3v.x, p);
            p = fmaf(silu_f(acc2[nt][1] + b2v.y), w3v.y, p);
            p = fmaf(silu_f(acc2[nt][2] + b2v.z), w3v.z, p);
            p = fmaf(silu_f(acc2[nt][3] + b2v.w), w3v.w, p);
        }
        p += __shfl_xor(p, 16);
        p += __shfl_xor(p, 32);

        // distributed coord-diff: lane (q,m) owns component q of edge m
        float cd = cr - cc;                        // q==3 lanes contribute 0
        float r2 = cd * cd;
        r2 += __shfl_xor(r2, 16);
        r2 += __shfl_xor(r2, 32);
        int e2 = g * 16 + m;
        if (e2 < E_ && q < 3) {
            float inv = __builtin_amdgcn_rcpf(sqrtf(r2 + 1e-8f) + 1.0f);
            atomicAdd(&out[rI * 3 + q], cd * (p * NORM_INV * inv));
        }
    }
}

extern "C" void kernel_launch(void* const* d_in, const int* in_sizes, int n_in,
                              void* d_out, int out_size, void* d_ws, size_t ws_size,
                              hipStream_t stream) {
    const float* h         = (const float*)d_in[0];
    const float* coord     = (const float*)d_in[1];
    const int*   eidx      = (const int*)  d_in[2];
    const float* edge_attr = (const float*)d_in[3];
    const float* W1        = (const float*)d_in[4];
    const float* b1        = (const float*)d_in[5];
    const float* W2        = (const float*)d_in[6];
    const float* b2        = (const float*)d_in[7];
    const float* W3        = (const float*)d_in[8];
    float* out = (float*)d_out;

    int E_ = in_sizes[2] / 2;    // edge_index is [2, E]
    int n3 = out_size;           // N*3

    hipLaunchKernelGGL(prep_out_kernel, dim3((n3 + 511) / 512), dim3(512), 0, stream,
                       coord, out, n3);
    hipLaunchKernelGGL(egnn_mfma_kernel, dim3(NBLK), dim3(NTH), 0, stream,
                       h, coord, eidx, edge_attr, W1, W2, b1, b2, W3, out, E_);
}

// Round 10
// 365.924 us; speedup vs baseline: 1.5151x; 1.5151x over previous
//
#include <hip/hip_runtime.h>
#include <math.h>

#define HD   64
#define EIN  8
#define SAS  168          // sW1 row stride in u16 (336 B): bank step 20 -> conflict-light
#define W2S  72           // sW2/X1 row stride in u16 (144 B)
#define NORM_INV 0.01f
#define NTH  256          // r5's proven concurrency: 4 waves/block
#define NBLK 768          // 3 blocks/CU x 256 CUs
#define NWAVES (NBLK * (NTH / 64))

typedef short bf16x8 __attribute__((ext_vector_type(8)));
typedef float f32x4  __attribute__((ext_vector_type(4)));
typedef float f4v    __attribute__((ext_vector_type(4)));

__device__ __forceinline__ unsigned short f2bf(float f) {
    union { float f; unsigned u; } v; v.f = f;
    unsigned r = v.u + 0x7FFFu + ((v.u >> 16) & 1u);
    return (unsigned short)(r >> 16);
}
__device__ __forceinline__ unsigned pk2(float a, float b) {
    return (unsigned)f2bf(a) | ((unsigned)f2bf(b) << 16);
}
__device__ __forceinline__ float silu_f(float x) {
    return x * __builtin_amdgcn_rcpf(1.0f + __expf(-x));
}

// prep: h -> bf16 table in ws + coord -> out copy
__global__ void prep_h_kernel(const float* __restrict__ h, unsigned short* __restrict__ hbf,
                              int npairs, const float* __restrict__ coord,
                              float* __restrict__ out, int n3) {
    int i = blockIdx.x * blockDim.x + threadIdx.x;
    if (i < npairs) {
        float2 v = reinterpret_cast<const float2*>(h)[i];
        ushort2 o; o.x = f2bf(v.x); o.y = f2bf(v.y);
        reinterpret_cast<ushort2*>(hbf)[i] = o;
    }
    if (i < n3) out[i] = coord[i];
}

__global__ void prep_out_kernel(const float* __restrict__ coord,
                                float* __restrict__ out, int n3) {
    int i = blockIdx.x * blockDim.x + threadIdx.x;
    if (i < n3) out[i] = coord[i];
}

// Direct-fragment variant of r5's barrier-free wave-owned pipeline:
// layer-1 B-fragments are loaded STRAIGHT from global (one 16 B load per
// lane per k-step) -- no A-tile LDS staging at all. Only X1 round-trips
// through LDS (layout change for layer 2). r5 concurrency (256 thr, 3/CU).
template <bool HB>
__global__ __launch_bounds__(NTH, 3) void egnn_mfma_kernel(
    const float* __restrict__ h,             // fp32 h (when !HB)
    const unsigned short* __restrict__ hbf,  // bf16 h table in ws (when HB)
    const float* __restrict__ coord,
    const int*   __restrict__ eidx,   // [2][E]
    const float* __restrict__ eattr,  // [E][8]
    const float* __restrict__ W1f,    // [136][64] fp32
    const float* __restrict__ W2f,    // [64][64] fp32
    const float* __restrict__ b1,
    const float* __restrict__ b2,
    const float* __restrict__ W3,
    float* __restrict__ out,
    int E_)
{
    __shared__ unsigned short sW1[64 * SAS];      // 21504 B
    __shared__ unsigned short sW2[64 * W2S];      //  9216 B
    __shared__ unsigned short sX1[64 * W2S];      //  9216 B (4 waves x 16 rows)
    __shared__ float sB1[64], sB2[64], sW3[64];   //   768 B

    const int t = threadIdx.x;

    // ---- weights -> LDS (once per block) ----
    for (int i = t; i < 136 * 64; i += NTH) {
        int k = i >> 6, n = i & 63;
        sW1[n * SAS + k] = f2bf(W1f[i]);
    }
    for (int i = t; i < 24 * 64; i += NTH) {      // zero-pad W1 k=136..159
        int n = i / 24, k = 136 + (i - n * 24);
        sW1[n * SAS + k] = 0;
    }
    for (int i = t; i < 64 * 64; i += NTH) {
        int k = i >> 6, n = i & 63;
        sW2[n * W2S + k] = f2bf(W2f[i]);
    }
    if (t < 64) sB1[t] = b1[t];
    else if (t < 128) sB2[t - 64] = b2[t - 64];
    else if (t < 192) sW3[t - 128] = W3[t - 128];
    __syncthreads();                               // the ONLY barrier

    const int w = t >> 6, lane = t & 63;
    const int m = lane & 15, q = lane >> 4;

    unsigned short* x1Row = sX1 + (16 * w + m) * W2S;  // this lane's edge row

    const int ngroups = (E_ + 15) >> 4;
    for (int g = blockIdx.x * (NTH / 64) + w; g < ngroups; g += NWAVES) {
        // ---------- per-lane edge indices (each lane owns edge m of group) ----------
        int e = g * 16 + m;
        int ec = (e < E_) ? e : (E_ - 1);
        int row = eidx[ec];
        int col = eidx[(size_t)E_ + ec];

        // coord loads issued early (latency hidden behind MFMA)
        float cr = 0.f, cc = 0.f;
        if (q < 3) { cr = coord[row * 3 + q]; cc = coord[col * 3 + q]; }

        // ---------- layer-1 B-fragments: one 16 B gather each ----------
        bf16x8 bf[5];
        if (HB) {
            const bf16x8* hr = (const bf16x8*)(hbf + (size_t)row * HD);
            const bf16x8* hc = (const bf16x8*)(hbf + (size_t)col * HD);
            bf[0] = hr[q];          // k =   q*8 .. +8
            bf[1] = hr[4 + q];      // k = 32+q*8
            bf[2] = hc[q];          // k = 64+...
            bf[3] = hc[4 + q];      // k = 96+...
        } else {
            const f4v* hr = (const f4v*)(h + (size_t)row * HD);
            const f4v* hc = (const f4v*)(h + (size_t)col * HD);
#pragma unroll
            for (int s = 0; s < 4; ++s) {
                const f4v* src = (s < 2) ? hr : hc;
                f4v a = src[(s & 1) * 8 + q * 2];
                f4v b = src[(s & 1) * 8 + q * 2 + 1];
                union { bf16x8 v; uint4 u; } pk;
                pk.u.x = pk2(a.x, a.y); pk.u.y = pk2(a.z, a.w);
                pk.u.z = pk2(b.x, b.y); pk.u.w = pk2(b.z, b.w);
                bf[s] = pk.v;
            }
        }
        {
            union { bf16x8 v; uint4 u; } pk;
            pk.u.x = 0; pk.u.y = 0; pk.u.z = 0; pk.u.w = 0;
            if (q == 0) {                       // k = 128..135: edge_attr
                f4v a0 = ((const f4v*)(eattr + (size_t)ec * EIN))[0];
                f4v a1 = ((const f4v*)(eattr + (size_t)ec * EIN))[1];
                pk.u.x = pk2(a0.x, a0.y); pk.u.y = pk2(a0.z, a0.w);
                pk.u.z = pk2(a1.x, a1.y); pk.u.w = pk2(a1.z, a1.w);
            }
            bf[4] = pk.v;                       // q>0: zeros (W1 pad also zero)
        }

        // ---------- layer 1: D1[n2][e] = sum_k W1[n2][k] * inp[e][k] ----------
        f32x4 acc1[4] = {};
#pragma unroll
        for (int s = 0; s < 5; ++s) {
#pragma unroll
            for (int nt = 0; nt < 4; ++nt) {
                bf16x8 afrag = *(const bf16x8*)(sW1 + (16 * nt + m) * SAS + s * 32 + q * 8);
                acc1[nt] = __builtin_amdgcn_mfma_f32_16x16x32_bf16(afrag, bf[s], acc1[nt], 0, 0, 0);
            }
        }

        // silu(+b1) -> X1[e][k] packed b64 per lane
#pragma unroll
        for (int nt = 0; nt < 4; ++nt) {
            float4 bb = *(const float4*)(&sB1[16 * nt + 4 * q]);
            ushort4 o;
            o.x = f2bf(silu_f(acc1[nt][0] + bb.x));
            o.y = f2bf(silu_f(acc1[nt][1] + bb.y));
            o.z = f2bf(silu_f(acc1[nt][2] + bb.z));
            o.w = f2bf(silu_f(acc1[nt][3] + bb.w));
            *((ushort4*)(x1Row + 16 * nt + 4 * q)) = o;
        }

        // ---------- layer 2: D2[n2][e] = sum_k W2[n2][k] * X1[e][k] ----------
        f32x4 acc2[4] = {};
#pragma unroll
        for (int s = 0; s < 2; ++s) {
            bf16x8 bfrag = *(const bf16x8*)(x1Row + s * 32 + q * 8);
#pragma unroll
            for (int nt = 0; nt < 4; ++nt) {
                bf16x8 afrag = *(const bf16x8*)(sW2 + (16 * nt + m) * W2S + s * 32 + q * 8);
                acc2[nt] = __builtin_amdgcn_mfma_f32_16x16x32_bf16(afrag, bfrag, acc2[nt], 0, 0, 0);
            }
        }

        // ---------- epilogue: scal = silu(X2) . W3, all in registers ----------
        float p = 0.f;
#pragma unroll
        for (int nt = 0; nt < 4; ++nt) {
            float4 b2v = *(const float4*)(&sB2[16 * nt + 4 * q]);
            float4 w3v = *(const float4*)(&sW3[16 * nt + 4 * q]);
            p = fmaf(silu_f(acc2[nt][0] + b2v.x), w3v.x, p);
            p = fmaf(silu_f(acc2[nt][1] + b2v.y), w3v.y, p);
            p = fmaf(silu_f(acc2[nt][2] + b2v.z), w3v.z, p);
            p = fmaf(silu_f(acc2[nt][3] + b2v.w), w3v.w, p);
        }
        p += __shfl_xor(p, 16);
        p += __shfl_xor(p, 32);

        // distributed coord-diff: lane (q,m) owns component q of edge m
        float cd = cr - cc;                        // q==3 lanes contribute 0
        float r2 = cd * cd;
        r2 += __shfl_xor(r2, 16);
        r2 += __shfl_xor(r2, 32);
        if (e < E_ && q < 3) {
            float inv = __builtin_amdgcn_rcpf(sqrtf(r2 + 1e-8f) + 1.0f);
            atomicAdd(&out[row * 3 + q], cd * (p * NORM_INV * inv));
        }
    }
}

extern "C" void kernel_launch(void* const* d_in, const int* in_sizes, int n_in,
                              void* d_out, int out_size, void* d_ws, size_t ws_size,
                              hipStream_t stream) {
    const float* h         = (const float*)d_in[0];
    const float* coord     = (const float*)d_in[1];
    const int*   eidx      = (const int*)  d_in[2];
    const float* edge_attr = (const float*)d_in[3];
    const float* W1        = (const float*)d_in[4];
    const float* b1        = (const float*)d_in[5];
    const float* W2        = (const float*)d_in[6];
    const float* b2        = (const float*)d_in[7];
    const float* W3        = (const float*)d_in[8];
    float* out = (float*)d_out;

    int E_ = in_sizes[2] / 2;    // edge_index is [2, E]
    int n3 = out_size;           // N*3
    int nf = in_sizes[0];        // N*HD floats of h

    if (ws_size >= (size_t)nf * 2) {             // bf16 h table (6.4 MB)
        unsigned short* hbf = (unsigned short*)d_ws;
        int npairs = nf / 2;
        int pgrid = (npairs > n3 ? npairs : n3);
        hipLaunchKernelGGL(prep_h_kernel, dim3((pgrid + 255) / 256), dim3(256), 0, stream,
                           h, hbf, npairs, coord, out, n3);
        hipLaunchKernelGGL((egnn_mfma_kernel<true>), dim3(NBLK), dim3(NTH), 0, stream,
                           h, hbf, coord, eidx, edge_attr, W1, W2, b1, b2, W3, out, E_);
    } else {
        hipLaunchKernelGGL(prep_out_kernel, dim3((n3 + 255) / 256), dim3(256), 0, stream,
                           coord, out, n3);
        hipLaunchKernelGGL((egnn_mfma_kernel<false>), dim3(NBLK), dim3(NTH), 0, stream,
                           h, (const unsigned short*)nullptr, coord, eidx, edge_attr,
                           W1, W2, b1, b2, W3, out, E_);
    }
}